// Round 5
// baseline (1681.007 us; speedup 1.0000x reference)
//
#include <hip/hip_runtime.h>
#include <hip/hip_bf16.h>

// ---------------------------------------------------------------------------
// GNN forward on MI355X, round 5.
// r1-r4 all measured ~80 us/phase vs ~1.1 us compute floor: exposed W-load
// latency at 1-2 waves/SIMD (VGPR-bound occupancy). r5 keeps r4's verified
// register-resident dataflow (perm-layout MFMA handoff) but sized for
// occupancy: 16 rows/wave, residual+base in VGPRs, no LDS, ~160 VGPR ->
// 3 waves/SIMD. Per-layer raw s_barrier keeps block waves on the same
// W-stream for L1 reuse.
// ---------------------------------------------------------------------------

#define H        128
#define FEAT     32
#define M_NODES  32768
#define L_LAYERS 16
#define MU_      (M_NODES / 2)

typedef __bf16 bf16x8 __attribute__((ext_vector_type(8)));
typedef float  f32x4  __attribute__((ext_vector_type(4)));

#define MFMA_BF16 __builtin_amdgcn_mfma_f32_16x16x32_bf16

// frag-pair slots in d_ws: 2 KB each (1 KB hi plane, 1 KB lo plane).
// frag (c,kt): lane l elem j holds W[c*16 + (l&15)][kt*32 + perm((l>>4)*8+j)]
// perm(k) = ((k&7)>>2)*16 + (k>>3)*4 + (k&3)  (bijection; makes D-layout ==
// next layer's B-frag layout -> zero-cost inter-layer handoff)
#define SLOT_EMB    0                  // K=32,  KT=1, 8 fps
#define SLOT_MPU(l) (8 + (l) * 32)     // K=128, KT=4, 5 layers
#define SLOT_MPB0   168                // K=256, KT=8
#define SLOT_MPB(l) (232 + (l) * 32)
#define SLOT_NE0    360                // K=256, KT=8
#define SLOT_NE(l)  (424 + (l) * 32)
#define TOTAL_FP    552

// ---------------------------------------------------------------------------
__global__ void prep_kernel(__bf16* __restrict__ frags,
                            const float* __restrict__ emb_w,
                            const float* __restrict__ mpu_w,
                            const float* __restrict__ mpb0_w,
                            const float* __restrict__ mpb_w,
                            const float* __restrict__ ne0_w,
                            const float* __restrict__ ne_w) {
  int fp = blockIdx.x * 4 + (threadIdx.x >> 6);
  if (fp >= TOTAL_FP) return;
  int lane = threadIdx.x & 63;
  int r16 = lane & 15, g = lane >> 4;
  const float* src; int K; int idx;
  if (fp < 8)        { src = emb_w;                             K = 32;  idx = fp; }
  else if (fp < 168) { src = mpu_w + ((fp - 8) >> 5) * H * H;   K = 128; idx = (fp - 8) & 31; }
  else if (fp < 232) { src = mpb0_w;                            K = 256; idx = fp - 168; }
  else if (fp < 360) { src = mpb_w + ((fp - 232) >> 5) * H * H; K = 128; idx = (fp - 232) & 31; }
  else if (fp < 424) { src = ne0_w;                             K = 256; idx = fp - 360; }
  else               { src = ne_w + ((fp - 424) >> 5) * H * H;  K = 128; idx = (fp - 424) & 31; }
  int KT = K >> 5;
  int c = idx / KT, kt = idx - c * KT;
  int col = c * 16 + r16;
  __bf16* dhi = frags + ((size_t)fp << 10) + lane * 8;
#pragma unroll
  for (int j = 0; j < 8; ++j) {
    int k = kt * 32 + ((j >> 2) * 16 + g * 4 + (j & 3));   // permuted k slot
    float x  = src[col * K + k];
    __bf16 h = (__bf16)x;
    dhi[j]       = h;
    dhi[512 + j] = (__bf16)(x - (float)h);
  }
}

// ---------------------------------------------------------------------------
__device__ __forceinline__ void split_pair(const f32x4& a, const f32x4& b,
                                           bf16x8& h, bf16x8& l) {
#pragma unroll
  for (int j = 0; j < 4; ++j) {
    __bf16 t = (__bf16)a[j]; h[j] = t;     l[j] = (__bf16)(a[j] - (float)t);
    __bf16 u = (__bf16)b[j]; h[4 + j] = u; l[4 + j] = (__bf16)(b[j] - (float)u);
  }
}

__device__ __forceinline__ void zero_acc8(f32x4 (&acc)[8]) {
  f32x4 z = {0.f, 0.f, 0.f, 0.f};
#pragma unroll
  for (int c = 0; c < 8; ++c) acc[c] = z;
}

// Build X frags (permuted layout) for one K=128 global f32 row (per lane r16).
__device__ __forceinline__ void row_frags128(bf16x8 (&xh)[4], bf16x8 (&xl)[4],
                                             const float* __restrict__ src, int g) {
#pragma unroll
  for (int kt = 0; kt < 4; ++kt) {
    f32x4 a = *(const f32x4*)(src + kt * 32 + g * 4);
    f32x4 b = *(const f32x4*)(src + kt * 32 + 16 + g * 4);
    split_pair(a, b, xh[kt], xl[kt]);
  }
}

// acc += split3( X(16 rows) @ W^T ), one K=128 pass. W streamed from L1/L2.
__device__ __forceinline__ void stage128(f32x4 (&acc)[8],
                                         const bf16x8 (&xh)[4], const bf16x8 (&xl)[4],
                                         const __bf16* __restrict__ frags,
                                         int fp0, int KT, int kt0, int lane) {
#pragma unroll
  for (int cp = 0; cp < 4; ++cp) {
    const int c0 = 2 * cp, c1 = 2 * cp + 1;
#pragma unroll
    for (int kt = 0; kt < 4; ++kt) {
      const __bf16* f0 = frags + (((size_t)(fp0 + c0 * KT + kt0 + kt)) << 10) + lane * 8;
      const __bf16* f1 = frags + (((size_t)(fp0 + c1 * KT + kt0 + kt)) << 10) + lane * 8;
      bf16x8 w0h = *(const bf16x8*)f0;
      bf16x8 w0l = *(const bf16x8*)(f0 + 512);
      bf16x8 w1h = *(const bf16x8*)f1;
      bf16x8 w1l = *(const bf16x8*)(f1 + 512);
      acc[c0] = MFMA_BF16(w0h, xh[kt], acc[c0], 0, 0, 0);
      acc[c1] = MFMA_BF16(w1h, xh[kt], acc[c1], 0, 0, 0);
      acc[c0] = MFMA_BF16(w0l, xh[kt], acc[c0], 0, 0, 0);
      acc[c1] = MFMA_BF16(w1l, xh[kt], acc[c1], 0, 0, 0);
      acc[c0] = MFMA_BF16(w0h, xl[kt], acc[c0], 0, 0, 0);
      acc[c1] = MFMA_BF16(w1h, xl[kt], acc[c1], 0, 0, 0);
    }
  }
}

// K=32 pass (embedding).
__device__ __forceinline__ void stage32(f32x4 (&acc)[8],
                                        const bf16x8& fh, const bf16x8& fl,
                                        const __bf16* __restrict__ frags, int fp0, int lane) {
#pragma unroll
  for (int cp = 0; cp < 4; ++cp) {
    const int c0 = 2 * cp, c1 = 2 * cp + 1;
    const __bf16* f0 = frags + (((size_t)(fp0 + c0)) << 10) + lane * 8;
    const __bf16* f1 = frags + (((size_t)(fp0 + c1)) << 10) + lane * 8;
    bf16x8 w0h = *(const bf16x8*)f0;
    bf16x8 w0l = *(const bf16x8*)(f0 + 512);
    bf16x8 w1h = *(const bf16x8*)f1;
    bf16x8 w1l = *(const bf16x8*)(f1 + 512);
    acc[c0] = MFMA_BF16(w0h, fh, acc[c0], 0, 0, 0);
    acc[c1] = MFMA_BF16(w1h, fh, acc[c1], 0, 0, 0);
    acc[c0] = MFMA_BF16(w0l, fh, acc[c0], 0, 0, 0);
    acc[c1] = MFMA_BF16(w1l, fh, acc[c1], 0, 0, 0);
    acc[c0] = MFMA_BF16(w0h, fl, acc[c0], 0, 0, 0);
    acc[c1] = MFMA_BF16(w1h, fl, acc[c1], 0, 0, 0);
  }
}

// relu(acc + bias) -> next-layer frags; residual bookkeeping in VGPRs.
// PM: 0 = write prev only (L0); 1 = x += prev, write prev (L1..L3);
//     2 = frags only (last layer of a stack / embed).
template <int PM>
__device__ __forceinline__ void epilogue_frags(const f32x4 (&acc)[8],
                                               const float* __restrict__ bias,
                                               f32x4 (&prev)[8], int g,
                                               bf16x8 (&xh)[4], bf16x8 (&xl)[4]) {
#pragma unroll
  for (int kt = 0; kt < 4; ++kt) {
    f32x4 x0, x1;
#pragma unroll
    for (int hf = 0; hf < 2; ++hf) {
      const int c = 2 * kt + hf;
      f32x4 bv = *(const f32x4*)(bias + c * 16 + g * 4);
      f32x4 a, x;
#pragma unroll
      for (int j = 0; j < 4; ++j) a[j] = fmaxf(acc[c][j] + bv[j], 0.f);
      x = a;
      if (PM == 1) {
#pragma unroll
        for (int j = 0; j < 4; ++j) x[j] = a[j] + prev[c][j];
      }
      if (PM != 2) prev[c] = a;
      if (hf == 0) x0 = x; else x1 = x;
    }
    split_pair(x0, x1, xh[kt], xl[kt]);
  }
}

__device__ __forceinline__ void epilogue_store(const f32x4 (&acc)[8],
                                               const float* __restrict__ bias,
                                               float* __restrict__ out, int r16, int g) {
#pragma unroll
  for (int c = 0; c < 8; ++c) {
    f32x4 bv = *(const f32x4*)(bias + c * 16 + g * 4);
    f32x4 v;
#pragma unroll
    for (int j = 0; j < 4; ++j) v[j] = fmaxf(acc[c][j] + bv[j], 0.f);
    *(f32x4*)(out + (size_t)r16 * H + c * 16 + g * 4) = v;
  }
}

// feats frags (K=32) for one row.
__device__ __forceinline__ void feats_frags(bf16x8& fh, bf16x8& fl,
                                            const float* __restrict__ feats,
                                            int row, int g) {
  const float* src = feats + (size_t)row * FEAT;
  f32x4 a = *(const f32x4*)(src + g * 4);
  f32x4 b = *(const f32x4*)(src + 16 + g * 4);
  split_pair(a, b, fh, fl);
}

// ---------------------------------------------------------------------------
__global__ __launch_bounds__(256, 4) void base0_kernel(float* __restrict__ E,
                                                       const float* __restrict__ feats,
                                                       const __bf16* __restrict__ frags,
                                                       const float* __restrict__ emb_b) {
  int tid = threadIdx.x, lane = tid & 63, wave = tid >> 6;
  int r16 = lane & 15, g = lane >> 4;
  int R0 = blockIdx.x * 64 + wave * 16;
  bf16x8 fh, fl;
  feats_frags(fh, fl, feats, R0 + r16, g);
  f32x4 acc[8];
  zero_acc8(acc);
  stage32(acc, fh, fl, frags, SLOT_EMB, lane);
  epilogue_store(acc, emb_b, E + (size_t)R0 * H, r16, g);
}

// ---------------------------------------------------------------------------
__global__ __launch_bounds__(256, 3) void phase_kernel(
    float* __restrict__ E, const int* __restrict__ parents,
    const __bf16* __restrict__ frags, const float* __restrict__ feats,
    const float* __restrict__ emb_b,
    const float* __restrict__ mpu_b, const float* __restrict__ mpb0_b,
    const float* __restrict__ mpb_b, const float* __restrict__ ne0_b,
    const float* __restrict__ ne_b, int s) {
  int tid = threadIdx.x, lane = tid & 63, wave = tid >> 6;
  int r16 = lane & 15, g = lane >> 4;
  int R0 = blockIdx.x * 64 + wave * 16;
  int gr = s + R0 + r16;

  f32x4 acc[8], prev[8];
  bf16x8 xh[4], xl[4];
  bf16x8 bh[4], bl[4];   // base frags, computed once, live until node-L0

  // ---- base = relu(emb(feats row)) in-register (embed fused) ----
  {
    bf16x8 fh, fl;
    feats_frags(fh, fl, feats, gr, g);
    zero_acc8(acc);
    stage32(acc, fh, fl, frags, SLOT_EMB, lane);
    epilogue_frags<2>(acc, emb_b, prev, g, bh, bl);
  }
  __builtin_amdgcn_s_barrier();

  // ---- redux chain ----
  if (R0 < MU_) {
    int p = parents[2 * gr];
    row_frags128(xh, xl, E + (size_t)p * H, g);
    zero_acc8(acc);
    stage128(acc, xh, xl, frags, SLOT_MPU(0), 4, 0, lane);
    epilogue_frags<0>(acc, mpu_b, prev, g, xh, xl);
    __builtin_amdgcn_s_barrier();
#pragma unroll 1
    for (int l = 1; l <= 3; ++l) {
      zero_acc8(acc);
      stage128(acc, xh, xl, frags, SLOT_MPU(l), 4, 0, lane);
      epilogue_frags<1>(acc, mpu_b + l * H, prev, g, xh, xl);
      __builtin_amdgcn_s_barrier();
    }
    zero_acc8(acc);
    stage128(acc, xh, xl, frags, SLOT_MPU(4), 4, 0, lane);
    epilogue_frags<2>(acc, mpu_b + 4 * H, prev, g, xh, xl);
  } else {
    int p0 = parents[2 * gr], p1 = parents[2 * gr + 1];
    row_frags128(xh, xl, E + (size_t)p0 * H, g);
    zero_acc8(acc);
    stage128(acc, xh, xl, frags, SLOT_MPB0, 8, 0, lane);   // k 0..127
    row_frags128(xh, xl, E + (size_t)p1 * H, g);
    stage128(acc, xh, xl, frags, SLOT_MPB0, 8, 4, lane);   // k 128..255
    epilogue_frags<0>(acc, mpb0_b, prev, g, xh, xl);
    __builtin_amdgcn_s_barrier();
#pragma unroll 1
    for (int l = 0; l <= 2; ++l) {
      zero_acc8(acc);
      stage128(acc, xh, xl, frags, SLOT_MPB(l), 4, 0, lane);
      epilogue_frags<1>(acc, mpb_b + l * H, prev, g, xh, xl);
      __builtin_amdgcn_s_barrier();
    }
    zero_acc8(acc);
    stage128(acc, xh, xl, frags, SLOT_MPB(3), 4, 0, lane);
    epilogue_frags<2>(acc, mpb_b + 3 * H, prev, g, xh, xl);
  }
  __builtin_amdgcn_s_barrier();

  // ---- node chain: x = [base | redux], L0 K=256 then 4 x K=128 ----
  zero_acc8(acc);
  stage128(acc, xh, xl, frags, SLOT_NE0, 8, 4, lane);  // redux half (k 128..255)
  stage128(acc, bh, bl, frags, SLOT_NE0, 8, 0, lane);  // base half  (k 0..127)
  epilogue_frags<0>(acc, ne0_b, prev, g, xh, xl);
  __builtin_amdgcn_s_barrier();
#pragma unroll 1
  for (int l = 0; l <= 2; ++l) {
    zero_acc8(acc);
    stage128(acc, xh, xl, frags, SLOT_NE(l), 4, 0, lane);
    epilogue_frags<1>(acc, ne_b + l * H, prev, g, xh, xl);
    __builtin_amdgcn_s_barrier();
  }
  zero_acc8(acc);
  stage128(acc, xh, xl, frags, SLOT_NE(3), 4, 0, lane);
  epilogue_store(acc, ne_b + 3 * H, E + (size_t)(s + R0) * H, r16, g);
}

// ---------------------------------------------------------------------------
extern "C" void kernel_launch(void* const* d_in, const int* in_sizes, int n_in,
                              void* d_out, int out_size, void* d_ws, size_t ws_size,
                              hipStream_t stream) {
  const float* node_feats = (const float*)d_in[0];
  const float* emb_w  = (const float*)d_in[1];
  const float* emb_b  = (const float*)d_in[2];
  const float* ne0_w  = (const float*)d_in[3];
  const float* ne0_b  = (const float*)d_in[4];
  const float* ne_w   = (const float*)d_in[5];
  const float* ne_b   = (const float*)d_in[6];
  const float* mpu_w  = (const float*)d_in[7];
  const float* mpu_b  = (const float*)d_in[8];
  const float* mpb0_w = (const float*)d_in[9];
  const float* mpb0_b = (const float*)d_in[10];
  const float* mpb_w  = (const float*)d_in[11];
  const float* mpb_b  = (const float*)d_in[12];
  const int*   parents = (const int*)d_in[13];
  float* E = (float*)d_out;
  __bf16* frags = (__bf16*)d_ws;   // 552 * 2048 B ~= 1.13 MB

  prep_kernel<<<(TOTAL_FP + 3) / 4, 256, 0, stream>>>(frags, emb_w, mpu_w, mpb0_w,
                                                      mpb_w, ne0_w, ne_w);
  base0_kernel<<<M_NODES / 64, 256, 0, stream>>>(E, node_feats, frags, emb_b);
  for (int l = 1; l < L_LAYERS; ++l) {
    phase_kernel<<<M_NODES / 64, 256, 0, stream>>>(E, parents, frags, node_feats,
                                                   emb_b, mpu_b, mpb0_b, mpb_b,
                                                   ne0_b, ne_b, l * M_NODES);
  }
}

// Round 6
// 970.683 us; speedup vs baseline: 1.7318x; 1.7318x over previous
//
#include <hip/hip_runtime.h>
#include <hip/hip_bf16.h>

// ---------------------------------------------------------------------------
// GNN forward on MI355X, round 6.
// Model fitting r1-r5: W-fragment L2 traffic = waves x ~750KB/phase dominated
// every round. Fix: stage W chunks (64 KB) into LDS ONCE PER BLOCK
// (global_load_lds, double-buffered, prefetch-before-compute); all 4 waves
// read W from LDS. Activation chain stays register-resident (r4/r5-verified
// perm-layout MFMA handoff). 32 rows/wave, 256 blocks, 144 KB LDS.
// ---------------------------------------------------------------------------

#define H        128
#define FEAT     32
#define M_NODES  32768
#define L_LAYERS 16
#define MU_      (M_NODES / 2)

typedef __bf16 bf16x8 __attribute__((ext_vector_type(8)));
typedef float  f32x4  __attribute__((ext_vector_type(4)));

#define MFMA_BF16 __builtin_amdgcn_mfma_f32_16x16x32_bf16

// d_ws frag layout: fp 0..7 = EMB (16 KB); then 17 chunks of 32 fps (64 KB).
// Each fp = 2 KB: 512 hi bf16 (lane*8), then 512 lo. Within a chunk,
// fp index = c*4 + kt (c = col-tile 0..7, kt = k-tile 0..3).
// chunk map: 0-4 mpu[l]; 5/6 mpb0 (k 0-127 / 128-255); 7-10 mpb[l];
//            11/12 ne0 (k 0-127 / 128-255); 13-16 ne[l].
#define TOTAL_FP 552
#define CH_GOFF(ci) ((size_t)(8 + (ci) * 32) * 1024)

// ---------------------------------------------------------------------------
__global__ void prep_kernel(__bf16* __restrict__ frags,
                            const float* __restrict__ emb_w,
                            const float* __restrict__ mpu_w,
                            const float* __restrict__ mpb0_w,
                            const float* __restrict__ mpb_w,
                            const float* __restrict__ ne0_w,
                            const float* __restrict__ ne_w) {
  int fp = blockIdx.x * 4 + (threadIdx.x >> 6);
  if (fp >= TOTAL_FP) return;
  int lane = threadIdx.x & 63;
  int r16 = lane & 15, g = lane >> 4;
  const float* src; int K, kbase, c, kt;
  if (fp < 8) { src = emb_w; K = 32; kbase = 0; c = fp; kt = 0; }
  else {
    int ch = (fp - 8) >> 5, idx = (fp - 8) & 31;
    c = idx >> 2; kt = idx & 3;
    if (ch < 5)        { src = mpu_w + ch * H * H;        K = 128; kbase = 0; }
    else if (ch == 5)  { src = mpb0_w;                    K = 256; kbase = 0; }
    else if (ch == 6)  { src = mpb0_w;                    K = 256; kbase = 128; }
    else if (ch < 11)  { src = mpb_w + (ch - 7) * H * H;  K = 128; kbase = 0; }
    else if (ch == 11) { src = ne0_w;                     K = 256; kbase = 0; }
    else if (ch == 12) { src = ne0_w;                     K = 256; kbase = 128; }
    else               { src = ne_w + (ch - 13) * H * H;  K = 128; kbase = 0; }
  }
  int col = c * 16 + r16;
  __bf16* dhi = frags + ((size_t)fp << 10) + lane * 8;
#pragma unroll
  for (int j = 0; j < 8; ++j) {
    int k = kbase + kt * 32 + ((j >> 2) * 16 + g * 4 + (j & 3));  // perm slot
    float x  = src[col * K + k];
    __bf16 h = (__bf16)x;
    dhi[j]       = h;
    dhi[512 + j] = (__bf16)(x - (float)h);
  }
}

// ---------------------------------------------------------------------------
__device__ __forceinline__ void split_pair(const f32x4& a, const f32x4& b,
                                           bf16x8& h, bf16x8& l) {
#pragma unroll
  for (int j = 0; j < 4; ++j) {
    __bf16 t = (__bf16)a[j]; h[j] = t;     l[j] = (__bf16)(a[j] - (float)t);
    __bf16 u = (__bf16)b[j]; h[4 + j] = u; l[4 + j] = (__bf16)(b[j] - (float)u);
  }
}

__device__ __forceinline__ void zero_acc(f32x4 (&acc)[2][8]) {
  f32x4 z = {0.f, 0.f, 0.f, 0.f};
#pragma unroll
  for (int i = 0; i < 2; ++i)
#pragma unroll
    for (int c = 0; c < 8; ++c) acc[i][c] = z;
}

// X frags (permuted layout) for two K=128 global f32 rows.
__device__ __forceinline__ void gather_frags128(bf16x8 (&xh)[2][4], bf16x8 (&xl)[2][4],
                                                const float* __restrict__ s0,
                                                const float* __restrict__ s1, int g) {
#pragma unroll
  for (int i = 0; i < 2; ++i) {
    const float* src = i ? s1 : s0;
#pragma unroll
    for (int kt = 0; kt < 4; ++kt) {
      f32x4 a = *(const f32x4*)(src + kt * 32 + g * 4);
      f32x4 b = *(const f32x4*)(src + kt * 32 + 16 + g * 4);
      split_pair(a, b, xh[i][kt], xl[i][kt]);
    }
  }
}

// acc += split3( X(32 rows) @ W^T ), one 32-fp chunk. wp = LDS (or global) base.
__device__ __forceinline__ void g128(f32x4 (&acc)[2][8],
                                     const bf16x8 (&xh)[2][4], const bf16x8 (&xl)[2][4],
                                     const __bf16* wp, int lane) {
#pragma unroll
  for (int cp = 0; cp < 4; ++cp) {
    const int c0 = 2 * cp, c1 = 2 * cp + 1;
#pragma unroll
    for (int kt = 0; kt < 4; ++kt) {
      const __bf16* f0 = wp + (size_t)(c0 * 4 + kt) * 1024 + lane * 8;
      const __bf16* f1 = wp + (size_t)(c1 * 4 + kt) * 1024 + lane * 8;
      bf16x8 w0h = *(const bf16x8*)f0;
      bf16x8 w0l = *(const bf16x8*)(f0 + 512);
      bf16x8 w1h = *(const bf16x8*)f1;
      bf16x8 w1l = *(const bf16x8*)(f1 + 512);
      acc[0][c0] = MFMA_BF16(w0h, xh[0][kt], acc[0][c0], 0, 0, 0);
      acc[0][c1] = MFMA_BF16(w1h, xh[0][kt], acc[0][c1], 0, 0, 0);
      acc[1][c0] = MFMA_BF16(w0h, xh[1][kt], acc[1][c0], 0, 0, 0);
      acc[1][c1] = MFMA_BF16(w1h, xh[1][kt], acc[1][c1], 0, 0, 0);
      acc[0][c0] = MFMA_BF16(w0l, xh[0][kt], acc[0][c0], 0, 0, 0);
      acc[0][c1] = MFMA_BF16(w1l, xh[0][kt], acc[0][c1], 0, 0, 0);
      acc[1][c0] = MFMA_BF16(w0l, xh[1][kt], acc[1][c0], 0, 0, 0);
      acc[1][c1] = MFMA_BF16(w1l, xh[1][kt], acc[1][c1], 0, 0, 0);
      acc[0][c0] = MFMA_BF16(w0h, xl[0][kt], acc[0][c0], 0, 0, 0);
      acc[0][c1] = MFMA_BF16(w1h, xl[0][kt], acc[0][c1], 0, 0, 0);
      acc[1][c0] = MFMA_BF16(w0h, xl[1][kt], acc[1][c0], 0, 0, 0);
      acc[1][c1] = MFMA_BF16(w1h, xl[1][kt], acc[1][c1], 0, 0, 0);
    }
  }
}

// K=32 embed pass (8 fps at wp).
__device__ __forceinline__ void stage32(f32x4 (&acc)[2][8],
                                        const bf16x8 (&fh)[2], const bf16x8 (&fl)[2],
                                        const __bf16* wp, int lane) {
#pragma unroll
  for (int cp = 0; cp < 4; ++cp) {
    const int c0 = 2 * cp, c1 = 2 * cp + 1;
    const __bf16* f0 = wp + (size_t)c0 * 1024 + lane * 8;
    const __bf16* f1 = wp + (size_t)c1 * 1024 + lane * 8;
    bf16x8 w0h = *(const bf16x8*)f0;
    bf16x8 w0l = *(const bf16x8*)(f0 + 512);
    bf16x8 w1h = *(const bf16x8*)f1;
    bf16x8 w1l = *(const bf16x8*)(f1 + 512);
    acc[0][c0] = MFMA_BF16(w0h, fh[0], acc[0][c0], 0, 0, 0);
    acc[0][c1] = MFMA_BF16(w1h, fh[0], acc[0][c1], 0, 0, 0);
    acc[1][c0] = MFMA_BF16(w0h, fh[1], acc[1][c0], 0, 0, 0);
    acc[1][c1] = MFMA_BF16(w1h, fh[1], acc[1][c1], 0, 0, 0);
    acc[0][c0] = MFMA_BF16(w0l, fh[0], acc[0][c0], 0, 0, 0);
    acc[0][c1] = MFMA_BF16(w1l, fh[0], acc[0][c1], 0, 0, 0);
    acc[1][c0] = MFMA_BF16(w0l, fh[1], acc[1][c0], 0, 0, 0);
    acc[1][c1] = MFMA_BF16(w1l, fh[1], acc[1][c1], 0, 0, 0);
    acc[0][c0] = MFMA_BF16(w0h, fl[0], acc[0][c0], 0, 0, 0);
    acc[0][c1] = MFMA_BF16(w1h, fl[0], acc[0][c1], 0, 0, 0);
    acc[1][c0] = MFMA_BF16(w0h, fl[1], acc[1][c0], 0, 0, 0);
    acc[1][c1] = MFMA_BF16(w1h, fl[1], acc[1][c1], 0, 0, 0);
  }
}

// relu(acc+bias) -> next-layer frags; residual prev in VGPRs.
// PM 0: write prev only; 1: x += prev, write prev; 2: frags only.
template <int PM>
__device__ __forceinline__ void epilogue_frags(const f32x4 (&acc)[2][8],
                                               const float* __restrict__ bias,
                                               f32x4 (&prev)[2][8], int g,
                                               bf16x8 (&xh)[2][4], bf16x8 (&xl)[2][4]) {
#pragma unroll
  for (int i = 0; i < 2; ++i)
#pragma unroll
    for (int kt = 0; kt < 4; ++kt) {
      f32x4 x0, x1;
#pragma unroll
      for (int hf = 0; hf < 2; ++hf) {
        const int c = 2 * kt + hf;
        f32x4 bv = *(const f32x4*)(bias + c * 16 + g * 4);
        f32x4 a, x;
#pragma unroll
        for (int j = 0; j < 4; ++j) a[j] = fmaxf(acc[i][c][j] + bv[j], 0.f);
        x = a;
        if (PM == 1) {
#pragma unroll
          for (int j = 0; j < 4; ++j) x[j] = a[j] + prev[i][c][j];
        }
        if (PM != 2) prev[i][c] = a;
        if (hf == 0) x0 = x; else x1 = x;
      }
      split_pair(x0, x1, xh[i][kt], xl[i][kt]);
    }
}

__device__ __forceinline__ void epilogue_store(const f32x4 (&acc)[2][8],
                                               const float* __restrict__ bias,
                                               float* __restrict__ out, int r16, int g) {
#pragma unroll
  for (int i = 0; i < 2; ++i)
#pragma unroll
    for (int c = 0; c < 8; ++c) {
      f32x4 bv = *(const f32x4*)(bias + c * 16 + g * 4);
      f32x4 v;
#pragma unroll
      for (int j = 0; j < 4; ++j) v[j] = fmaxf(acc[i][c][j] + bv[j], 0.f);
      *(f32x4*)(out + (size_t)(i * 16 + r16) * H + c * 16 + g * 4) = v;
    }
}

__device__ __forceinline__ void feats_frags(bf16x8 (&fh)[2], bf16x8 (&fl)[2],
                                            const float* __restrict__ feats,
                                            int row_a, int row_b, int g) {
#pragma unroll
  for (int i = 0; i < 2; ++i) {
    const float* src = feats + (size_t)(i ? row_b : row_a) * FEAT;
    f32x4 a = *(const f32x4*)(src + g * 4);
    f32x4 b = *(const f32x4*)(src + 16 + g * 4);
    split_pair(a, b, fh[i], fl[i]);
  }
}

// async global->LDS staging: n4k x 4KB, 256 threads x 16B each.
__device__ __forceinline__ void stage_lds(const __bf16* __restrict__ gsrc,
                                          __bf16* ldst, int tid, int n4k) {
#pragma unroll
  for (int i = 0; i < 16; ++i) {
    if (i >= n4k) break;
    int off = (i * 256 + tid) * 8;   // elems; 16 B per thread
    __builtin_amdgcn_global_load_lds(
        (const __attribute__((address_space(1))) unsigned int*)(gsrc + off),
        (__attribute__((address_space(3))) unsigned int*)(ldst + off), 16, 0, 0);
  }
}

// ---------------------------------------------------------------------------
__global__ __launch_bounds__(256, 1) void base0_kernel(float* __restrict__ E,
                                                       const float* __restrict__ feats,
                                                       const __bf16* __restrict__ frags,
                                                       const float* __restrict__ emb_b) {
  int tid = threadIdx.x, lane = tid & 63, wave = tid >> 6;
  int r16 = lane & 15, g = lane >> 4;
  int R0 = blockIdx.x * 128 + wave * 32;
  bf16x8 fh[2], fl[2];
  feats_frags(fh, fl, feats, R0 + r16, R0 + 16 + r16, g);
  f32x4 acc[2][8];
  zero_acc(acc);
  stage32(acc, fh, fl, frags, lane);   // EMB fps 0..7, read from global (L2)
  epilogue_store(acc, emb_b, E + (size_t)R0 * H, r16, g);
}

// ---------------------------------------------------------------------------
__global__ __launch_bounds__(256, 1) void phase_kernel(
    float* __restrict__ E, const int* __restrict__ parents,
    const __bf16* __restrict__ frags, const float* __restrict__ feats,
    const float* __restrict__ emb_b,
    const float* __restrict__ mpu_b, const float* __restrict__ mpb0_b,
    const float* __restrict__ mpb_b, const float* __restrict__ ne0_b,
    const float* __restrict__ ne_b, int s) {
  __shared__ __bf16 wbuf[2][32 * 1024];   // 2 x 64 KB W chunks
  __shared__ __bf16 wemb[8 * 1024];       // 16 KB embed W
  int tid = threadIdx.x, lane = tid & 63, wave = tid >> 6;
  int r16 = lane & 15, g = lane >> 4;
  int R0 = blockIdx.x * 128 + wave * 32;
  int gra = s + R0 + r16, grb = gra + 16;

  f32x4 acc[2][8], prev[2][8];
  bf16x8 xh[2][4], xl[2][4];

#define STG(ci, b) stage_lds(frags + CH_GOFF(ci), wbuf[b], tid, 16)

  if (blockIdx.x < 128) {
    // ======================= unary half =======================
    stage_lds(frags, wemb, tid, 4);
    STG(0, 0);
    int pa = parents[2 * gra], pb = parents[2 * grb];
    gather_frags128(xh, xl, E + (size_t)pa * H, E + (size_t)pb * H, g);
    __syncthreads();
    // MPU0
    STG(1, 1); zero_acc(acc); g128(acc, xh, xl, wbuf[0], lane);
    epilogue_frags<0>(acc, mpu_b, prev, g, xh, xl); __syncthreads();
    // MPU1
    STG(2, 0); zero_acc(acc); g128(acc, xh, xl, wbuf[1], lane);
    epilogue_frags<1>(acc, mpu_b + H, prev, g, xh, xl); __syncthreads();
    // MPU2
    STG(3, 1); zero_acc(acc); g128(acc, xh, xl, wbuf[0], lane);
    epilogue_frags<1>(acc, mpu_b + 2 * H, prev, g, xh, xl); __syncthreads();
    // MPU3
    STG(4, 0); zero_acc(acc); g128(acc, xh, xl, wbuf[1], lane);
    epilogue_frags<1>(acc, mpu_b + 3 * H, prev, g, xh, xl); __syncthreads();
    // MPU4 -> redux result
    STG(12, 1); zero_acc(acc); g128(acc, xh, xl, wbuf[0], lane);
    epilogue_frags<2>(acc, mpu_b + 4 * H, prev, g, xh, xl); __syncthreads();
  } else {
    // ======================= binary half =======================
    stage_lds(frags, wemb, tid, 4);
    STG(5, 0);
    int p0a = parents[2 * gra], p1a = parents[2 * gra + 1];
    int p0b = parents[2 * grb], p1b = parents[2 * grb + 1];
    gather_frags128(xh, xl, E + (size_t)p0a * H, E + (size_t)p0b * H, g);
    __syncthreads();
    // MPB0 k 0..127 (E[p0])
    STG(6, 1); zero_acc(acc); g128(acc, xh, xl, wbuf[0], lane);
    gather_frags128(xh, xl, E + (size_t)p1a * H, E + (size_t)p1b * H, g);
    __syncthreads();
    // MPB0 k 128..255 (E[p1])
    STG(7, 0); g128(acc, xh, xl, wbuf[1], lane);
    epilogue_frags<0>(acc, mpb0_b, prev, g, xh, xl); __syncthreads();
    // MPB_0
    STG(8, 1); zero_acc(acc); g128(acc, xh, xl, wbuf[0], lane);
    epilogue_frags<1>(acc, mpb_b, prev, g, xh, xl); __syncthreads();
    // MPB_1
    STG(9, 0); zero_acc(acc); g128(acc, xh, xl, wbuf[1], lane);
    epilogue_frags<1>(acc, mpb_b + H, prev, g, xh, xl); __syncthreads();
    // MPB_2
    STG(10, 1); zero_acc(acc); g128(acc, xh, xl, wbuf[0], lane);
    epilogue_frags<1>(acc, mpb_b + 2 * H, prev, g, xh, xl); __syncthreads();
    // MPB_3 -> redux result
    STG(12, 0); zero_acc(acc); g128(acc, xh, xl, wbuf[1], lane);
    epilogue_frags<2>(acc, mpb_b + 3 * H, prev, g, xh, xl); __syncthreads();
  }

  // ---- node chain (identical for both halves) ----
  // buffers on entry: unary computed wbuf[0] last, chunk12 staged in wbuf[1];
  //                   binary computed wbuf[1] last, chunk12 staged in wbuf[0].
  if (blockIdx.x < 128) {
    // NE0 redux half (chunk12 @ wbuf[1]) + in-register base build
    STG(11, 0); zero_acc(acc); g128(acc, xh, xl, wbuf[1], lane);
    { bf16x8 fh[2], fl[2];
      feats_frags(fh, fl, feats, gra, grb, g);
      f32x4 acc2[2][8]; zero_acc(acc2);
      stage32(acc2, fh, fl, wemb, lane);
      epilogue_frags<2>(acc2, emb_b, prev, g, xh, xl); }   // x := base frags
    __syncthreads();
    // NE0 base half (chunk11 @ wbuf[0])
    STG(13, 1); g128(acc, xh, xl, wbuf[0], lane);
    epilogue_frags<0>(acc, ne0_b, prev, g, xh, xl); __syncthreads();
    // NE_0
    STG(14, 0); zero_acc(acc); g128(acc, xh, xl, wbuf[1], lane);
    epilogue_frags<1>(acc, ne_b, prev, g, xh, xl); __syncthreads();
    // NE_1
    STG(15, 1); zero_acc(acc); g128(acc, xh, xl, wbuf[0], lane);
    epilogue_frags<1>(acc, ne_b + H, prev, g, xh, xl); __syncthreads();
    // NE_2
    STG(16, 0); zero_acc(acc); g128(acc, xh, xl, wbuf[1], lane);
    epilogue_frags<1>(acc, ne_b + 2 * H, prev, g, xh, xl); __syncthreads();
    // NE_3 -> store
    zero_acc(acc); g128(acc, xh, xl, wbuf[0], lane);
    epilogue_store(acc, ne_b + 3 * H, E + (size_t)(s + R0) * H, r16, g);
  } else {
    // NE0 redux half (chunk12 @ wbuf[0]) + base build
    STG(11, 1); zero_acc(acc); g128(acc, xh, xl, wbuf[0], lane);
    { bf16x8 fh[2], fl[2];
      feats_frags(fh, fl, feats, gra, grb, g);
      f32x4 acc2[2][8]; zero_acc(acc2);
      stage32(acc2, fh, fl, wemb, lane);
      epilogue_frags<2>(acc2, emb_b, prev, g, xh, xl); }
    __syncthreads();
    // NE0 base half (chunk11 @ wbuf[1])
    STG(13, 0); g128(acc, xh, xl, wbuf[1], lane);
    epilogue_frags<0>(acc, ne0_b, prev, g, xh, xl); __syncthreads();
    // NE_0
    STG(14, 1); zero_acc(acc); g128(acc, xh, xl, wbuf[0], lane);
    epilogue_frags<1>(acc, ne_b, prev, g, xh, xl); __syncthreads();
    // NE_1
    STG(15, 0); zero_acc(acc); g128(acc, xh, xl, wbuf[1], lane);
    epilogue_frags<1>(acc, ne_b + H, prev, g, xh, xl); __syncthreads();
    // NE_2
    STG(16, 1); zero_acc(acc); g128(acc, xh, xl, wbuf[0], lane);
    epilogue_frags<1>(acc, ne_b + 2 * H, prev, g, xh, xl); __syncthreads();
    // NE_3 -> store
    zero_acc(acc); g128(acc, xh, xl, wbuf[1], lane);
    epilogue_store(acc, ne_b + 3 * H, E + (size_t)(s + R0) * H, r16, g);
  }
#undef STG
}

// ---------------------------------------------------------------------------
extern "C" void kernel_launch(void* const* d_in, const int* in_sizes, int n_in,
                              void* d_out, int out_size, void* d_ws, size_t ws_size,
                              hipStream_t stream) {
  const float* node_feats = (const float*)d_in[0];
  const float* emb_w  = (const float*)d_in[1];
  const float* emb_b  = (const float*)d_in[2];
  const float* ne0_w  = (const float*)d_in[3];
  const float* ne0_b  = (const float*)d_in[4];
  const float* ne_w   = (const float*)d_in[5];
  const float* ne_b   = (const float*)d_in[6];
  const float* mpu_w  = (const float*)d_in[7];
  const float* mpu_b  = (const float*)d_in[8];
  const float* mpb0_w = (const float*)d_in[9];
  const float* mpb0_b = (const float*)d_in[10];
  const float* mpb_w  = (const float*)d_in[11];
  const float* mpb_b  = (const float*)d_in[12];
  const int*   parents = (const int*)d_in[13];
  float* E = (float*)d_out;
  __bf16* frags = (__bf16*)d_ws;   // 552 * 2048 B ~= 1.13 MB

  prep_kernel<<<(TOTAL_FP + 3) / 4, 256, 0, stream>>>(frags, emb_w, mpu_w, mpb0_w,
                                                      mpb_w, ne0_w, ne_w);
  base0_kernel<<<M_NODES / 128, 256, 0, stream>>>(E, node_feats, frags, emb_b);
  for (int l = 1; l < L_LAYERS; ++l) {
    phase_kernel<<<M_NODES / 128, 256, 0, stream>>>(E, parents, frags, node_feats,
                                                    emb_b, mpu_b, mpb0_b, mpb_b,
                                                    ne0_b, ne_b, l * M_NODES);
  }
}